// Round 5
// baseline (706.066 us; speedup 1.0000x reference)
//
#include <hip/hip_runtime.h>

#define NN      50000
#define NEDGE   1600000
#define NA      1000000
#define FEATD   128
#define EMBD    64
#define MAXSEND 50
#define RSTR    136   // padded LDS row stride in BYTES (128 fp8 + 8 pad)

// ---- binned CSR build parameters ----
#define BSHIFT  7                 // 128 nodes per bin
#define NBINS   391               // ceil(50000/128)
#define BINCAP  4864              // mean 4096 + ~12 sigma headroom
#define ACHUNK  4096              // edges staged per block in k_binA
#define ABLK    391               // ceil(NEDGE/ACHUNK)

typedef __attribute__((ext_vector_type(4))) float f32x4;
typedef __attribute__((ext_vector_type(2))) float f32x2;

__device__ __forceinline__ unsigned char f2fp8(float f) {
    int p = __builtin_amdgcn_cvt_pk_fp8_f32(f, f, 0, false);
    return (unsigned char)(p & 0xff);
}

__device__ __forceinline__ int wave_incl_scan(int v, int lane) {
#pragma unroll
    for (int d = 1; d < 64; d <<= 1) {
        int u = __shfl_up(v, d, 64);
        v += (lane >= d) ? u : 0;
    }
    return v;
}

// ---------------- phase A: block-staged scatter of (row,col) into coarse bins ----------------
__launch_bounds__(512)
__global__ void k_binA(const int* __restrict__ row, const int* __restrict__ col,
                       int* __restrict__ bincnt, int2* __restrict__ epair) {
    extern __shared__ char smem[];
    int2* buf   = (int2*)smem;                        // ACHUNK * 8 bytes
    int*  hist  = (int*)(smem + ACHUNK * sizeof(int2));
    int*  lcur  = hist + NBINS;
    int*  delta = lcur + NBINS;
    __shared__ int ws8[8];

    int tid = threadIdx.x;
    for (int i = tid; i < NBINS; i += 512) hist[i] = 0;
    __syncthreads();

    int base = blockIdx.x * ACHUNK;
    int myr[8], myc[8];
#pragma unroll
    for (int j = 0; j < 8; j++) {
        int e = base + j * 512 + tid;
        myc[j] = (e < NEDGE) ? col[e] : -1;
        myr[j] = (e < NEDGE) ? row[e] : 0;
        if (myc[j] >= 0) atomicAdd(&hist[myc[j] >> BSHIFT], 1);
    }
    __syncthreads();

    // exclusive scan of hist (391 values) + reserve global space per bin
    int lane = tid & 63, w = tid >> 6;
    int v = (tid < NBINS) ? hist[tid] : 0;
    int inc = wave_incl_scan(v, lane);
    if (lane == 63) ws8[w] = inc;
    __syncthreads();
    if (tid < NBINS) {
        int add = 0;
        for (int i = 0; i < w; i++) add += ws8[i];
        int excl = add + inc - v;
        lcur[tid] = excl;
        int prior = (v > 0) ? atomicAdd(&bincnt[tid], v) : 0;
        delta[tid] = tid * BINCAP + prior - excl;     // LDS slot s -> global pos s + delta[bin]
    }
    __syncthreads();

    // local scatter into LDS, ordered by bin
#pragma unroll
    for (int j = 0; j < 8; j++) {
        if (myc[j] >= 0) {
            int b = myc[j] >> BSHIFT;
            int p = atomicAdd(&lcur[b], 1);
            buf[p] = make_int2(myr[j], myc[j]);
        }
    }
    __syncthreads();

    // coalesced run-writes to global bins
    int total = min(ACHUNK, NEDGE - base);
    for (int s = tid; s < total; s += 512) {
        int2 pr = buf[s];
        epair[s + delta[pr.y >> BSHIFT]] = pr;
    }
}

// ---------------- exclusive scan of bin totals (391 values, 1 block) ----------------
__global__ void k_binscan(const int* __restrict__ bincnt, int* __restrict__ binbase) {
    int t = threadIdx.x;                               // 512 threads
    int v = (t < NBINS) ? bincnt[t] : 0;
    int lane = t & 63, w = t >> 6;
    int inc = wave_incl_scan(v, lane);
    __shared__ int ws8[8];
    if (lane == 63) ws8[w] = inc;
    __syncthreads();
    int add = 0;
    for (int i = 0; i < w; i++) add += ws8[i];
    if (t < NBINS) binbase[t] = add + inc - v;
}

// ---------------- phase B: one block per bin -> off, dinv, esrc ----------------
__launch_bounds__(512)
__global__ void k_binB(const int* __restrict__ bincnt, const int* __restrict__ binbase,
                       const int2* __restrict__ epair,
                       int* __restrict__ off, float* __restrict__ dinv,
                       int* __restrict__ esrc) {
    __shared__ int hist[128];
    __shared__ int lcur[128];
    __shared__ int ws8[8];
    int b = blockIdx.x;
    int tid = threadIdx.x;
    int nodes0 = b << BSHIFT;
    int nnodes = min(128, NN - nodes0);
    int n = bincnt[b];
    const int2* src = epair + (long)b * BINCAP;

    if (tid < 128) hist[tid] = 0;
    __syncthreads();
    for (int s = tid; s < n; s += 512)
        atomicAdd(&hist[src[s].y & 127], 1);
    __syncthreads();

    int lane = tid & 63, w = tid >> 6;
    int v = (tid < 128) ? hist[tid] : 0;
    int inc = wave_incl_scan(v, lane);
    if (lane == 63) ws8[w] = inc;
    __syncthreads();
    if (tid < 128) {
        int add = binbase[b];
        for (int i = 0; i < w; i++) add += ws8[i];
        int excl = add + inc - v;
        lcur[tid] = excl;
        if (tid < nnodes) {
            off[nodes0 + tid]  = excl;
            dinv[nodes0 + tid] = rsqrtf((float)(v + 1));   // +1 self loop
        }
    }
    if (b == 0 && tid == 0) off[NN] = NEDGE;
    __syncthreads();

    for (int s = tid; s < n; s += 512) {
        int2 pr = src[s];
        int p = atomicAdd(&lcur[pr.y & 127], 1);
        esrc[p] = pr.x;
    }
}

// ---------------- node GEMM: Hs[v][j] = dinv[v] * sum_k X[v][k] W[k][j] ----------------
__global__ void k_gemm_nodes(const float* __restrict__ X, const float* __restrict__ W,
                             const float* __restrict__ dinv, float* __restrict__ Hs) {
    int wid  = (blockIdx.x * 256 + threadIdx.x) >> 6;  // one wave per node row
    int lane = threadIdx.x & 63;
    const float* xr = X + (long)wid * FEATD;
    float x0 = xr[lane];
    float x1 = xr[lane + 64];
    float acc = 0.f;
#pragma unroll
    for (int k = 0; k < 64; k++) {
        float xv = __shfl(x0, k, 64);
        acc = fmaf(xv, W[k * EMBD + lane], acc);
    }
#pragma unroll
    for (int k = 0; k < 64; k++) {
        float xv = __shfl(x1, k, 64);
        acc = fmaf(xv, W[(k + 64) * EMBD + lane], acc);
    }
    Hs[(long)wid * EMBD + lane] = acc * dinv[wid];
}

// ---- gather layer 1 fused with layer-2 node GEMM ----
__global__ void k_gather1(const float* __restrict__ Hs, const int* __restrict__ off,
                          const int* __restrict__ esrc, const float* __restrict__ dinv,
                          const float* __restrict__ b1, const float* __restrict__ W2,
                          float* __restrict__ Hs2) {
    int wid  = (blockIdx.x * 256 + threadIdx.x) >> 6;  // one wave per node
    int lane = threadIdx.x & 63;
    int beg = off[wid], end = off[wid + 1];
    float acc = Hs[(long)wid * EMBD + lane];           // self loop
    int i = beg;
    for (; i + 4 <= end; i += 4) {
        int r0 = esrc[i], r1 = esrc[i + 1], r2 = esrc[i + 2], r3 = esrc[i + 3];
        acc += Hs[(long)r0 * EMBD + lane] + Hs[(long)r1 * EMBD + lane]
             + Hs[(long)r2 * EMBD + lane] + Hs[(long)r3 * EMBD + lane];
    }
    for (; i < end; i++) acc += Hs[(long)esrc[i] * EMBD + lane];
    float d = dinv[wid];
    float h = fmaxf(acc * d + b1[lane], 0.f);
    float a2 = 0.f;
#pragma unroll
    for (int k = 0; k < 64; k++) {
        float hv = __shfl(h, k, 64);
        a2 = fmaf(hv, W2[k * EMBD + lane], a2);
    }
    Hs2[(long)wid * EMBD + lane] = a2 * d;
}

// ---- gather layer 2 fused with placement head + fp8 emb pack ----
__global__ void k_gather2(const float* __restrict__ Hs, const int* __restrict__ off,
                          const int* __restrict__ esrc, const float* __restrict__ dinv,
                          const float* __restrict__ b2,
                          const float* __restrict__ Wp1, const float* __restrict__ bp1,
                          const float* __restrict__ Wp2, const float* __restrict__ bp2,
                          float* __restrict__ out_place, unsigned char* __restrict__ emb8) {
    int wid  = (blockIdx.x * 256 + threadIdx.x) >> 6;  // one wave per node
    int lane = threadIdx.x & 63;
    int beg = off[wid], end = off[wid + 1];
    float acc = Hs[(long)wid * EMBD + lane];
    int i = beg;
    for (; i + 4 <= end; i += 4) {
        int r0 = esrc[i], r1 = esrc[i + 1], r2 = esrc[i + 2], r3 = esrc[i + 3];
        acc += Hs[(long)r0 * EMBD + lane] + Hs[(long)r1 * EMBD + lane]
             + Hs[(long)r2 * EMBD + lane] + Hs[(long)r3 * EMBD + lane];
    }
    for (; i < end; i++) acc += Hs[(long)esrc[i] * EMBD + lane];
    float o = acc * dinv[wid] + b2[lane];              // emb value (fp32)
    // placement head
    float p = 0.f;
#pragma unroll
    for (int k = 0; k < 64; k++) {
        float ev = __shfl(o, k, 64);
        p = fmaf(ev, Wp1[k * 64 + lane], p);
    }
    p = fmaxf(p + bp1[lane], 0.f) * Wp2[lane];
#pragma unroll
    for (int d = 32; d; d >>= 1) p += __shfl_xor(p, d, 64);
    if (lane == 0) out_place[wid] = p + bp2[0];
    // fp8 pack of emb row (4 lanes -> 1 dword)
    float o1 = __shfl_down(o, 1, 64);
    float o2 = __shfl_down(o, 2, 64);
    float o3 = __shfl_down(o, 3, 64);
    int pk = __builtin_amdgcn_cvt_pk_fp8_f32(o, o1, 0, false);
    pk = __builtin_amdgcn_cvt_pk_fp8_f32(o2, o3, pk, true);
    if ((lane & 3) == 0)
        *(int*)(emb8 + (long)wid * EMBD + lane) = pk;
}

// ---- weight prep: fp8 transposed [n][k]; n: 0-63 We1, 64-191 Wa1, 192-255 Wa2(pad) ----
__global__ void k_prep(const float* __restrict__ We1, const float* __restrict__ Wa1,
                       const float* __restrict__ Wa2, unsigned char* __restrict__ Wt8) {
    int t = blockIdx.x * 256 + threadIdx.x;
    if (t >= 256 * 128) return;
    int n = t >> 7, k = t & 127;
    float v;
    if (n < 64)       v = We1[k * 64 + n];
    else if (n < 192) v = Wa1[k * 128 + (n - 64)];
    else { int n2 = n - 192; v = (n2 < MAXSEND) ? Wa2[k * MAXSEND + n2] : 0.f; }
    Wt8[t] = f2fp8(v);
}

// ---------------- action-edge MLP: fp8 MFMA, one 16-action m-tile per wave ----------------
// Latency-bound fix (R4): software-pipeline the serial ae->army->emb8 load chain
// (next tile's ae load issued at iteration top, dependent army/emb8 loads issued
// right after stage-1 MFMA), and store army tile directly (R0 style) but
// NON-TEMPORAL (keeps R3's fetch win without R2/R3's extra LDS drains).
__launch_bounds__(512, 4)
__global__ void k_action(const unsigned char* __restrict__ emb8, const int* __restrict__ ae,
                         const int* __restrict__ army, const unsigned char* __restrict__ Wt8,
                         const float* __restrict__ be1, const float* __restrict__ We2,
                         const float* __restrict__ be2, const float* __restrict__ ba1,
                         const float* __restrict__ ba2,
                         float* __restrict__ out_edge, float* __restrict__ out_army) {
    extern __shared__ char lds8[];
    int tid = threadIdx.x;
    // stage fp8 weights into padded LDS (256 rows x RSTR bytes)
    for (int i = tid; i < 2048; i += 512) {
        int rw = i >> 3, c16 = (i & 7) * 16;
        *(uint4*)(lds8 + rw * RSTR + c16) = *(const uint4*)(Wt8 + rw * 128 + c16);
    }
    __syncthreads();

    int w = tid >> 6, lane = tid & 63;
    int m = lane & 15, q = lane >> 4;                  // MFMA lane decomposition
    char* a1s = lds8 + 256 * RSTR + w * 16 * RSTR;     // per-wave 16xRSTR scratch (2176 B)

    float be1v[4], w2v[4], ba1v[8], ba2v[4];
#pragma unroll
    for (int t = 0; t < 4; t++) { be1v[t] = be1[t * 16 + m]; w2v[t] = We2[t * 16 + m]; }
#pragma unroll
    for (int t = 0; t < 8; t++) ba1v[t] = ba1[t * 16 + m];
#pragma unroll
    for (int nt = 0; nt < 4; nt++) { int n = nt * 16 + m; ba2v[nt] = (n < MAXSEND) ? ba2[n] : 0.f; }
    float be2v = be2[0];
    const f32x4 zero = {0.f, 0.f, 0.f, 0.f};

    int gw = blockIdx.x * 8 + w;
    int nwaves = gridDim.x * 8;
    const int NT = NA / 16;

    // ---- pipeline prologue: load tile 0's operands ----
    int tile = gw;
    int2 st = {0, 0};
    int army_s = 0, army_t = 0;
    long af[4] = {0, 0, 0, 0};
    if (tile < NT) {
        st = ((const int2*)ae)[tile * 16 + m];
        army_s = army[st.x];
        army_t = army[st.y];
        af[0] = *(const long*)(emb8 + (long)st.x * EMBD + q * 8);
        af[1] = *(const long*)(emb8 + (long)st.x * EMBD + 32 + q * 8);
        af[2] = *(const long*)(emb8 + (long)st.y * EMBD + q * 8);
        af[3] = *(const long*)(emb8 + (long)st.y * EMBD + 32 + q * 8);
    }

    while (tile < NT) {
        int a0 = tile * 16;
        int next = tile + nwaves;
        // early-issue next tile's ae pair (latency hides under stage-1 MFMA)
        int2 st_n = st;
        if (next < NT) st_n = ((const int2*)ae)[next * 16 + m];

        // per-action mask adjustment from current regs
        float adj_m = ((army_s <= 2) || (army_t >= 3 * army_s)) ? 1.f : 0.f;
        if (st.x == st.y) adj_m += 100.f;
        float adjr[4]; int sar[4];
#pragma unroll
        for (int r = 0; r < 4; r++) {
            int rowlane = q * 4 + r;
            adjr[r] = __shfl(adj_m, rowlane, 64);
            sar[r]  = __shfl(army_s, rowlane, 64);
        }

        // stage 1: n-tiles 0..3 -> e1 (We1 rows), 4..11 -> a1 (Wa1 rows)
        f32x4 acc[12];
#pragma unroll
        for (int t = 0; t < 12; t++) acc[t] = zero;
#pragma unroll
        for (int t = 0; t < 12; t++) {
#pragma unroll
            for (int kk = 0; kk < 4; kk++) {
                long bfrag = *(const long*)(lds8 + (t * 16 + m) * RSTR + kk * 32 + q * 8);
                acc[t] = __builtin_amdgcn_mfma_f32_16x16x32_fp8_fp8(af[kk], bfrag, acc[t], 0, 0, 0);
            }
        }

        // issue next tile's dependent loads NOW (st_n has landed during stage-1);
        // their latency hides under epilogues + stage-2
        int army_s_n = army_s, army_t_n = army_t;
        long af_n[4] = {af[0], af[1], af[2], af[3]};
        if (next < NT) {
            army_s_n = army[st_n.x];
            army_t_n = army[st_n.y];
            af_n[0] = *(const long*)(emb8 + (long)st_n.x * EMBD + q * 8);
            af_n[1] = *(const long*)(emb8 + (long)st_n.x * EMBD + 32 + q * 8);
            af_n[2] = *(const long*)(emb8 + (long)st_n.y * EMBD + q * 8);
            af_n[3] = *(const long*)(emb8 + (long)st_n.y * EMBD + 32 + q * 8);
        }

        // e1 epilogue -> edge-logit partials (C layout: row a=q*4+r, col j=t*16+m)
        float elp[4] = {0.f, 0.f, 0.f, 0.f};
#pragma unroll
        for (int t = 0; t < 4; t++) {
#pragma unroll
            for (int r = 0; r < 4; r++) {
                float v = fmaxf(acc[t][r] + be1v[t], 0.f);
                elp[r] = fmaf(v, w2v[t], elp[r]);
            }
        }
        // a1 epilogue -> fp8 into per-wave LDS scratch
#pragma unroll
        for (int t = 4; t < 12; t++) {
#pragma unroll
            for (int r = 0; r < 4; r++) {
                float v = fmaxf(acc[t][r] + ba1v[t - 4], 0.f);
                a1s[(q * 4 + r) * RSTR + (t - 4) * 16 + m] = (char)f2fp8(v);
            }
        }
        // reduce edge logits over the 16 j-lanes in each quad
#pragma unroll
        for (int r = 0; r < 4; r++) {
            float s = elp[r];
            s += __shfl_xor(s, 1, 64);
            s += __shfl_xor(s, 2, 64);
            s += __shfl_xor(s, 4, 64);
            s += __shfl_xor(s, 8, 64);
            elp[r] = s;
        }
        if (m == 0) {
#pragma unroll
            for (int r = 0; r < 4; r++)
                __builtin_nontemporal_store(elp[r] + be2v - adjr[r],
                                            &out_edge[a0 + q * 4 + r]);
        }
        __asm__ volatile("s_waitcnt lgkmcnt(0)" ::: "memory");  // a1s writes -> reads
        // stage 2: army = relu(a1) @ Wa2 (rows 192..255 in LDS, cols padded to 64)
        long a2f[4];
#pragma unroll
        for (int kk = 0; kk < 4; kk++)
            a2f[kk] = *(const long*)(a1s + m * RSTR + kk * 32 + q * 8);
#pragma unroll
        for (int nt = 0; nt < 4; nt++) {
            f32x4 c2 = zero;
#pragma unroll
            for (int kk = 0; kk < 4; kk++) {
                long bfrag = *(const long*)(lds8 + (192 + nt * 16 + m) * RSTR + kk * 32 + q * 8);
                c2 = __builtin_amdgcn_mfma_f32_16x16x32_fp8_fp8(a2f[kk], bfrag, c2, 0, 0, 0);
            }
            int n = nt * 16 + m;
            if (n < MAXSEND) {
#pragma unroll
                for (int r = 0; r < 4; r++) {
                    int aa = a0 + q * 4 + r;
                    float v = c2[r] + ba2v[nt];
                    __builtin_nontemporal_store((n < sar[r]) ? v : -1e9f,
                                                &out_army[(long)aa * MAXSEND + n]);
                }
            }
        }

        // rotate pipeline registers
        st = st_n; army_s = army_s_n; army_t = army_t_n;
        af[0] = af_n[0]; af[1] = af_n[1]; af[2] = af_n[2]; af[3] = af_n[3];
        tile = next;
    }
}

extern "C" void kernel_launch(void* const* d_in, const int* in_sizes, int n_in,
                              void* d_out, int out_size, void* d_ws, size_t ws_size,
                              hipStream_t stream) {
    const float* x    = (const float*)d_in[0];
    const int*   ei   = (const int*)d_in[1];
    const int*   ae   = (const int*)d_in[2];
    const int*   army = (const int*)d_in[3];
    const float* W1   = (const float*)d_in[4];
    const float* b1   = (const float*)d_in[5];
    const float* W2   = (const float*)d_in[6];
    const float* b2   = (const float*)d_in[7];
    const float* Wp1  = (const float*)d_in[8];
    const float* bp1  = (const float*)d_in[9];
    const float* Wp2  = (const float*)d_in[10];
    const float* bp2  = (const float*)d_in[11];
    const float* We1  = (const float*)d_in[12];
    const float* be1  = (const float*)d_in[13];
    const float* We2  = (const float*)d_in[14];
    const float* be2  = (const float*)d_in[15];
    const float* Wa1  = (const float*)d_in[16];
    const float* ba1  = (const float*)d_in[17];
    const float* Wa2  = (const float*)d_in[18];
    const float* ba2  = (const float*)d_in[19];
    float* out = (float*)d_out;

    char* ws = (char*)d_ws;
    int*           bincnt  = (int*)ws;                        // 391 ints
    int*           binbase = (int*)(ws + 4096);               // 391 ints
    float*         dinv    = (float*)(ws + 200000);           // 50000 f
    int*           off     = (int*)(ws + 400000);             // 50001 ints
    int*           esrc    = (int*)(ws + 800064);             // 1.6M ints
    int2*          epair   = (int2*)(ws + 7200064);           // 391*4864*8 = 15.2MB (transient)
    float*         A       = (float*)(ws + 7200064);          // 50000x64 f (Hs1) - after epair dead
    float*         B       = (float*)(ws + 20000064);         // 50000x64 f (Hs2)
    unsigned char* emb8    = (unsigned char*)(ws + 32800064); // 50000x64 fp8
    unsigned char* Wt8     = (unsigned char*)(ws + 36000064); // 256x128 fp8

    // ---- CSR build (once per launch): block-staged two-level binning sort ----
    hipMemsetAsync(bincnt, 0, NBINS * 4, stream);
    k_binA<<<ABLK, 512, ACHUNK * sizeof(int2) + 3 * NBINS * 4, stream>>>(
        ei, ei + NEDGE, bincnt, epair);
    k_binscan<<<1, 512, 0, stream>>>(bincnt, binbase);
    k_binB<<<NBINS, 512, 0, stream>>>(bincnt, binbase, epair, off, dinv, esrc);

    // ---- GCN layer 1 GEMM, then fused gather1+GEMM2, fused gather2+placement ----
    k_gemm_nodes<<<12500, 256, 0, stream>>>(x, W1, dinv, A);
    k_gather1<<<12500, 256, 0, stream>>>(A, off, esrc, dinv, b1, W2, B);
    k_gather2<<<12500, 256, 0, stream>>>(B, off, esrc, dinv, b2, Wp1, bp1, Wp2, bp2,
                                         out, emb8);

    // ---- action head (fp8 MFMA) ----
    k_prep<<<128, 256, 0, stream>>>(We1, Wa1, Wa2, Wt8);
    k_action<<<768, 512, 256 * RSTR + 8 * 16 * RSTR, stream>>>(
        emb8, ae, army, Wt8, be1, We2, be2, ba1, ba2, out + NN, out + NN + NA);
}

// Round 6
// 611.875 us; speedup vs baseline: 1.1539x; 1.1539x over previous
//
#include <hip/hip_runtime.h>

#define NN      50000
#define NEDGE   1600000
#define NA      1000000
#define FEATD   128
#define EMBD    64
#define MAXSEND 50
#define RSTR    136   // padded LDS row stride in BYTES (128 fp8 + 8 pad)

// ---- binned CSR build parameters ----
#define BSHIFT  7                 // 128 nodes per bin
#define NBINS   391               // ceil(50000/128)
#define BINCAP  4864              // mean 4096 + ~12 sigma headroom
#define ACHUNK  4096              // edges staged per block in k_binA
#define ABLK    391               // ceil(NEDGE/ACHUNK)

typedef __attribute__((ext_vector_type(4))) float f32x4;

__device__ __forceinline__ unsigned char f2fp8(float f) {
    int p = __builtin_amdgcn_cvt_pk_fp8_f32(f, f, 0, false);
    return (unsigned char)(p & 0xff);
}

__device__ __forceinline__ int wave_incl_scan(int v, int lane) {
#pragma unroll
    for (int d = 1; d < 64; d <<= 1) {
        int u = __shfl_up(v, d, 64);
        v += (lane >= d) ? u : 0;
    }
    return v;
}

// ---------------- phase A: block-staged scatter of (row,col) into coarse bins ----------------
__launch_bounds__(512)
__global__ void k_binA(const int* __restrict__ row, const int* __restrict__ col,
                       int* __restrict__ bincnt, int2* __restrict__ epair) {
    extern __shared__ char smem[];
    int2* buf   = (int2*)smem;                        // ACHUNK * 8 bytes
    int*  hist  = (int*)(smem + ACHUNK * sizeof(int2));
    int*  lcur  = hist + NBINS;
    int*  delta = lcur + NBINS;
    __shared__ int ws8[8];

    int tid = threadIdx.x;
    for (int i = tid; i < NBINS; i += 512) hist[i] = 0;
    __syncthreads();

    int base = blockIdx.x * ACHUNK;
    int myr[8], myc[8];
#pragma unroll
    for (int j = 0; j < 8; j++) {
        int e = base + j * 512 + tid;
        myc[j] = (e < NEDGE) ? col[e] : -1;
        myr[j] = (e < NEDGE) ? row[e] : 0;
        if (myc[j] >= 0) atomicAdd(&hist[myc[j] >> BSHIFT], 1);
    }
    __syncthreads();

    // exclusive scan of hist (391 values) + reserve global space per bin
    int lane = tid & 63, w = tid >> 6;
    int v = (tid < NBINS) ? hist[tid] : 0;
    int inc = wave_incl_scan(v, lane);
    if (lane == 63) ws8[w] = inc;
    __syncthreads();
    if (tid < NBINS) {
        int add = 0;
        for (int i = 0; i < w; i++) add += ws8[i];
        int excl = add + inc - v;
        lcur[tid] = excl;
        int prior = (v > 0) ? atomicAdd(&bincnt[tid], v) : 0;
        delta[tid] = tid * BINCAP + prior - excl;     // LDS slot s -> global pos s + delta[bin]
    }
    __syncthreads();

    // local scatter into LDS, ordered by bin
#pragma unroll
    for (int j = 0; j < 8; j++) {
        if (myc[j] >= 0) {
            int b = myc[j] >> BSHIFT;
            int p = atomicAdd(&lcur[b], 1);
            buf[p] = make_int2(myr[j], myc[j]);
        }
    }
    __syncthreads();

    // coalesced run-writes to global bins
    int total = min(ACHUNK, NEDGE - base);
    for (int s = tid; s < total; s += 512) {
        int2 pr = buf[s];
        epair[s + delta[pr.y >> BSHIFT]] = pr;
    }
}

// ---------------- exclusive scan of bin totals (391 values, 1 block) ----------------
__global__ void k_binscan(const int* __restrict__ bincnt, int* __restrict__ binbase) {
    int t = threadIdx.x;                               // 512 threads
    int v = (t < NBINS) ? bincnt[t] : 0;
    int lane = t & 63, w = t >> 6;
    int inc = wave_incl_scan(v, lane);
    __shared__ int ws8[8];
    if (lane == 63) ws8[w] = inc;
    __syncthreads();
    int add = 0;
    for (int i = 0; i < w; i++) add += ws8[i];
    if (t < NBINS) binbase[t] = add + inc - v;
}

// ---------------- phase B: one block per bin -> off, dinv, esrc ----------------
__launch_bounds__(512)
__global__ void k_binB(const int* __restrict__ bincnt, const int* __restrict__ binbase,
                       const int2* __restrict__ epair,
                       int* __restrict__ off, float* __restrict__ dinv,
                       int* __restrict__ esrc) {
    __shared__ int hist[128];
    __shared__ int lcur[128];
    __shared__ int ws8[8];
    int b = blockIdx.x;
    int tid = threadIdx.x;
    int nodes0 = b << BSHIFT;
    int nnodes = min(128, NN - nodes0);
    int n = bincnt[b];
    const int2* src = epair + (long)b * BINCAP;

    if (tid < 128) hist[tid] = 0;
    __syncthreads();
    for (int s = tid; s < n; s += 512)
        atomicAdd(&hist[src[s].y & 127], 1);
    __syncthreads();

    int lane = tid & 63, w = tid >> 6;
    int v = (tid < 128) ? hist[tid] : 0;
    int inc = wave_incl_scan(v, lane);
    if (lane == 63) ws8[w] = inc;
    __syncthreads();
    if (tid < 128) {
        int add = binbase[b];
        for (int i = 0; i < w; i++) add += ws8[i];
        int excl = add + inc - v;
        lcur[tid] = excl;
        if (tid < nnodes) {
            off[nodes0 + tid]  = excl;
            dinv[nodes0 + tid] = rsqrtf((float)(v + 1));   // +1 self loop
        }
    }
    if (b == 0 && tid == 0) off[NN] = NEDGE;
    __syncthreads();

    for (int s = tid; s < n; s += 512) {
        int2 pr = src[s];
        int p = atomicAdd(&lcur[pr.y & 127], 1);
        esrc[p] = pr.x;
    }
}

// ---------------- node GEMM: Hs[v][j] = dinv[v] * sum_k X[v][k] W[k][j] ----------------
__global__ void k_gemm_nodes(const float* __restrict__ X, const float* __restrict__ W,
                             const float* __restrict__ dinv, float* __restrict__ Hs) {
    int wid  = (blockIdx.x * 256 + threadIdx.x) >> 6;  // one wave per node row
    int lane = threadIdx.x & 63;
    const float* xr = X + (long)wid * FEATD;
    float x0 = xr[lane];
    float x1 = xr[lane + 64];
    float acc = 0.f;
#pragma unroll
    for (int k = 0; k < 64; k++) {
        float xv = __shfl(x0, k, 64);
        acc = fmaf(xv, W[k * EMBD + lane], acc);
    }
#pragma unroll
    for (int k = 0; k < 64; k++) {
        float xv = __shfl(x1, k, 64);
        acc = fmaf(xv, W[(k + 64) * EMBD + lane], acc);
    }
    Hs[(long)wid * EMBD + lane] = acc * dinv[wid];
}

// ---- gather layer 1 fused with layer-2 node GEMM ----
__global__ void k_gather1(const float* __restrict__ Hs, const int* __restrict__ off,
                          const int* __restrict__ esrc, const float* __restrict__ dinv,
                          const float* __restrict__ b1, const float* __restrict__ W2,
                          float* __restrict__ Hs2) {
    int wid  = (blockIdx.x * 256 + threadIdx.x) >> 6;  // one wave per node
    int lane = threadIdx.x & 63;
    int beg = off[wid], end = off[wid + 1];
    float acc = Hs[(long)wid * EMBD + lane];           // self loop
    int i = beg;
    for (; i + 4 <= end; i += 4) {
        int r0 = esrc[i], r1 = esrc[i + 1], r2 = esrc[i + 2], r3 = esrc[i + 3];
        acc += Hs[(long)r0 * EMBD + lane] + Hs[(long)r1 * EMBD + lane]
             + Hs[(long)r2 * EMBD + lane] + Hs[(long)r3 * EMBD + lane];
    }
    for (; i < end; i++) acc += Hs[(long)esrc[i] * EMBD + lane];
    float d = dinv[wid];
    float h = fmaxf(acc * d + b1[lane], 0.f);
    float a2 = 0.f;
#pragma unroll
    for (int k = 0; k < 64; k++) {
        float hv = __shfl(h, k, 64);
        a2 = fmaf(hv, W2[k * EMBD + lane], a2);
    }
    Hs2[(long)wid * EMBD + lane] = a2 * d;
}

// ---- gather layer 2 fused with placement head + fp8 emb pack ----
__global__ void k_gather2(const float* __restrict__ Hs, const int* __restrict__ off,
                          const int* __restrict__ esrc, const float* __restrict__ dinv,
                          const float* __restrict__ b2,
                          const float* __restrict__ Wp1, const float* __restrict__ bp1,
                          const float* __restrict__ Wp2, const float* __restrict__ bp2,
                          float* __restrict__ out_place, unsigned char* __restrict__ emb8) {
    int wid  = (blockIdx.x * 256 + threadIdx.x) >> 6;  // one wave per node
    int lane = threadIdx.x & 63;
    int beg = off[wid], end = off[wid + 1];
    float acc = Hs[(long)wid * EMBD + lane];
    int i = beg;
    for (; i + 4 <= end; i += 4) {
        int r0 = esrc[i], r1 = esrc[i + 1], r2 = esrc[i + 2], r3 = esrc[i + 3];
        acc += Hs[(long)r0 * EMBD + lane] + Hs[(long)r1 * EMBD + lane]
             + Hs[(long)r2 * EMBD + lane] + Hs[(long)r3 * EMBD + lane];
    }
    for (; i < end; i++) acc += Hs[(long)esrc[i] * EMBD + lane];
    float o = acc * dinv[wid] + b2[lane];              // emb value (fp32)
    // placement head
    float p = 0.f;
#pragma unroll
    for (int k = 0; k < 64; k++) {
        float ev = __shfl(o, k, 64);
        p = fmaf(ev, Wp1[k * 64 + lane], p);
    }
    p = fmaxf(p + bp1[lane], 0.f) * Wp2[lane];
#pragma unroll
    for (int d = 32; d; d >>= 1) p += __shfl_xor(p, d, 64);
    if (lane == 0) out_place[wid] = p + bp2[0];
    // fp8 pack of emb row (4 lanes -> 1 dword)
    float o1 = __shfl_down(o, 1, 64);
    float o2 = __shfl_down(o, 2, 64);
    float o3 = __shfl_down(o, 3, 64);
    int pk = __builtin_amdgcn_cvt_pk_fp8_f32(o, o1, 0, false);
    pk = __builtin_amdgcn_cvt_pk_fp8_f32(o2, o3, pk, true);
    if ((lane & 3) == 0)
        *(int*)(emb8 + (long)wid * EMBD + lane) = pk;
}

// ---- weight prep: fp8 transposed [n][k]; n: 0-63 We1, 64-191 Wa1, 192-255 Wa2(pad) ----
__global__ void k_prep(const float* __restrict__ We1, const float* __restrict__ Wa1,
                       const float* __restrict__ Wa2, unsigned char* __restrict__ Wt8) {
    int t = blockIdx.x * 256 + threadIdx.x;
    if (t >= 256 * 128) return;
    int n = t >> 7, k = t & 127;
    float v;
    if (n < 64)       v = We1[k * 64 + n];
    else if (n < 192) v = Wa1[k * 128 + (n - 64)];
    else { int n2 = n - 192; v = (n2 < MAXSEND) ? Wa2[k * MAXSEND + n2] : 0.f; }
    Wt8[t] = f2fp8(v);
}

// ---------------- action-edge MLP: fp8 MFMA, one 16-action m-tile per wave ----------------
// R5: R0's store scheme EXACTLY (scattered REGULAR stores -> L2 merges to full lines;
// R4 proved nt+scattered = 2.2x write amp) + R4's software pipeline of the serial
// ae->army->emb8 load chain (next ae at loop top under stage-1 MFMA; dependent
// army/emb8 loads after stage-1, hidden under epilogue+stage-2).
__launch_bounds__(512, 4)
__global__ void k_action(const unsigned char* __restrict__ emb8, const int* __restrict__ ae,
                         const int* __restrict__ army, const unsigned char* __restrict__ Wt8,
                         const float* __restrict__ be1, const float* __restrict__ We2,
                         const float* __restrict__ be2, const float* __restrict__ ba1,
                         const float* __restrict__ ba2,
                         float* __restrict__ out_edge, float* __restrict__ out_army) {
    extern __shared__ char lds8[];
    int tid = threadIdx.x;
    // stage fp8 weights into padded LDS (256 rows x RSTR bytes)
    for (int i = tid; i < 2048; i += 512) {
        int rw = i >> 3, c16 = (i & 7) * 16;
        *(uint4*)(lds8 + rw * RSTR + c16) = *(const uint4*)(Wt8 + rw * 128 + c16);
    }
    __syncthreads();

    int w = tid >> 6, lane = tid & 63;
    int m = lane & 15, q = lane >> 4;                  // MFMA lane decomposition
    char* a1s = lds8 + 256 * RSTR + w * 16 * RSTR;     // per-wave 16xRSTR fp8 scratch

    float be1v[4], w2v[4], ba1v[8], ba2v[4];
#pragma unroll
    for (int t = 0; t < 4; t++) { be1v[t] = be1[t * 16 + m]; w2v[t] = We2[t * 16 + m]; }
#pragma unroll
    for (int t = 0; t < 8; t++) ba1v[t] = ba1[t * 16 + m];
#pragma unroll
    for (int nt = 0; nt < 4; nt++) { int n = nt * 16 + m; ba2v[nt] = (n < MAXSEND) ? ba2[n] : 0.f; }
    float be2v = be2[0];
    const f32x4 zero = {0.f, 0.f, 0.f, 0.f};

    int gw = blockIdx.x * 8 + w;
    int nwaves = gridDim.x * 8;
    const int NT = NA / 16;

    // ---- pipeline prologue: load tile 0's operands ----
    int tile = gw;
    int2 st = {0, 0};
    int army_s = 0, army_t = 0;
    long af[4] = {0, 0, 0, 0};
    if (tile < NT) {
        st = ((const int2*)ae)[tile * 16 + m];
        army_s = army[st.x];
        army_t = army[st.y];
        af[0] = *(const long*)(emb8 + (long)st.x * EMBD + q * 8);
        af[1] = *(const long*)(emb8 + (long)st.x * EMBD + 32 + q * 8);
        af[2] = *(const long*)(emb8 + (long)st.y * EMBD + q * 8);
        af[3] = *(const long*)(emb8 + (long)st.y * EMBD + 32 + q * 8);
    }

    while (tile < NT) {
        int a0 = tile * 16;
        int next = tile + nwaves;
        // early-issue next tile's ae pair (latency hides under stage-1 MFMA)
        int2 st_n = st;
        if (next < NT) st_n = ((const int2*)ae)[next * 16 + m];

        // per-action mask adjustment from current regs
        float adj_m = ((army_s <= 2) || (army_t >= 3 * army_s)) ? 1.f : 0.f;
        if (st.x == st.y) adj_m += 100.f;
        float adjr[4]; int sar[4];
#pragma unroll
        for (int r = 0; r < 4; r++) {
            int rowlane = q * 4 + r;
            adjr[r] = __shfl(adj_m, rowlane, 64);
            sar[r]  = __shfl(army_s, rowlane, 64);
        }

        // stage 1: n-tiles 0..3 -> e1 (We1 rows), 4..11 -> a1 (Wa1 rows)
        f32x4 acc[12];
#pragma unroll
        for (int t = 0; t < 12; t++) acc[t] = zero;
#pragma unroll
        for (int t = 0; t < 12; t++) {
#pragma unroll
            for (int kk = 0; kk < 4; kk++) {
                long bfrag = *(const long*)(lds8 + (t * 16 + m) * RSTR + kk * 32 + q * 8);
                acc[t] = __builtin_amdgcn_mfma_f32_16x16x32_fp8_fp8(af[kk], bfrag, acc[t], 0, 0, 0);
            }
        }

        // issue next tile's dependent loads NOW (st_n landed during stage-1);
        // their latency hides under epilogues + stage-2
        int army_s_n = army_s, army_t_n = army_t;
        long af_n[4] = {af[0], af[1], af[2], af[3]};
        if (next < NT) {
            army_s_n = army[st_n.x];
            army_t_n = army[st_n.y];
            af_n[0] = *(const long*)(emb8 + (long)st_n.x * EMBD + q * 8);
            af_n[1] = *(const long*)(emb8 + (long)st_n.x * EMBD + 32 + q * 8);
            af_n[2] = *(const long*)(emb8 + (long)st_n.y * EMBD + q * 8);
            af_n[3] = *(const long*)(emb8 + (long)st_n.y * EMBD + 32 + q * 8);
        }

        // e1 epilogue -> edge-logit partials (C layout: row a=q*4+r, col j=t*16+m)
        float elp[4] = {0.f, 0.f, 0.f, 0.f};
#pragma unroll
        for (int t = 0; t < 4; t++) {
#pragma unroll
            for (int r = 0; r < 4; r++) {
                float v = fmaxf(acc[t][r] + be1v[t], 0.f);
                elp[r] = fmaf(v, w2v[t], elp[r]);
            }
        }
        // a1 epilogue -> fp8 into per-wave LDS scratch
#pragma unroll
        for (int t = 4; t < 12; t++) {
#pragma unroll
            for (int r = 0; r < 4; r++) {
                float v = fmaxf(acc[t][r] + ba1v[t - 4], 0.f);
                a1s[(q * 4 + r) * RSTR + (t - 4) * 16 + m] = (char)f2fp8(v);
            }
        }
        // reduce edge logits over the 16 j-lanes in each quad
#pragma unroll
        for (int r = 0; r < 4; r++) {
            float s = elp[r];
            s += __shfl_xor(s, 1, 64);
            s += __shfl_xor(s, 2, 64);
            s += __shfl_xor(s, 4, 64);
            s += __shfl_xor(s, 8, 64);
            elp[r] = s;
        }
        if (m == 0) {
#pragma unroll
            for (int r = 0; r < 4; r++)
                out_edge[a0 + q * 4 + r] = elp[r] + be2v - adjr[r];
        }
        __asm__ volatile("s_waitcnt lgkmcnt(0)" ::: "memory");  // a1s writes -> reads
        // stage 2: army = relu(a1) @ Wa2 (rows 192..255 in LDS, cols padded to 64)
        long a2f[4];
#pragma unroll
        for (int kk = 0; kk < 4; kk++)
            a2f[kk] = *(const long*)(a1s + m * RSTR + kk * 32 + q * 8);
#pragma unroll
        for (int nt = 0; nt < 4; nt++) {
            f32x4 c2 = zero;
#pragma unroll
            for (int kk = 0; kk < 4; kk++) {
                long bfrag = *(const long*)(lds8 + (192 + nt * 16 + m) * RSTR + kk * 32 + q * 8);
                c2 = __builtin_amdgcn_mfma_f32_16x16x32_fp8_fp8(a2f[kk], bfrag, c2, 0, 0, 0);
            }
            int n = nt * 16 + m;
            if (n < MAXSEND) {
#pragma unroll
                for (int r = 0; r < 4; r++) {
                    int aa = a0 + q * 4 + r;
                    float v = c2[r] + ba2v[nt];
                    out_army[(long)aa * MAXSEND + n] = (n < sar[r]) ? v : -1e9f;
                }
            }
        }

        // rotate pipeline registers
        st = st_n; army_s = army_s_n; army_t = army_t_n;
        af[0] = af_n[0]; af[1] = af_n[1]; af[2] = af_n[2]; af[3] = af_n[3];
        tile = next;
    }
}

extern "C" void kernel_launch(void* const* d_in, const int* in_sizes, int n_in,
                              void* d_out, int out_size, void* d_ws, size_t ws_size,
                              hipStream_t stream) {
    const float* x    = (const float*)d_in[0];
    const int*   ei   = (const int*)d_in[1];
    const int*   ae   = (const int*)d_in[2];
    const int*   army = (const int*)d_in[3];
    const float* W1   = (const float*)d_in[4];
    const float* b1   = (const float*)d_in[5];
    const float* W2   = (const float*)d_in[6];
    const float* b2   = (const float*)d_in[7];
    const float* Wp1  = (const float*)d_in[8];
    const float* bp1  = (const float*)d_in[9];
    const float* Wp2  = (const float*)d_in[10];
    const float* bp2  = (const float*)d_in[11];
    const float* We1  = (const float*)d_in[12];
    const float* be1  = (const float*)d_in[13];
    const float* We2  = (const float*)d_in[14];
    const float* be2  = (const float*)d_in[15];
    const float* Wa1  = (const float*)d_in[16];
    const float* ba1  = (const float*)d_in[17];
    const float* Wa2  = (const float*)d_in[18];
    const float* ba2  = (const float*)d_in[19];
    float* out = (float*)d_out;

    char* ws = (char*)d_ws;
    int*           bincnt  = (int*)ws;                        // 391 ints
    int*           binbase = (int*)(ws + 4096);               // 391 ints
    float*         dinv    = (float*)(ws + 200000);           // 50000 f
    int*           off     = (int*)(ws + 400000);             // 50001 ints
    int*           esrc    = (int*)(ws + 800064);             // 1.6M ints
    int2*          epair   = (int2*)(ws + 7200064);           // 391*4864*8 = 15.2MB (transient)
    float*         A       = (float*)(ws + 7200064);          // 50000x64 f (Hs1) - after epair dead
    float*         B       = (float*)(ws + 20000064);         // 50000x64 f (Hs2)
    unsigned char* emb8    = (unsigned char*)(ws + 32800064); // 50000x64 fp8
    unsigned char* Wt8     = (unsigned char*)(ws + 36000064); // 256x128 fp8

    // ---- CSR build (once per launch): block-staged two-level binning sort ----
    hipMemsetAsync(bincnt, 0, NBINS * 4, stream);
    k_binA<<<ABLK, 512, ACHUNK * sizeof(int2) + 3 * NBINS * 4, stream>>>(
        ei, ei + NEDGE, bincnt, epair);
    k_binscan<<<1, 512, 0, stream>>>(bincnt, binbase);
    k_binB<<<NBINS, 512, 0, stream>>>(bincnt, binbase, epair, off, dinv, esrc);

    // ---- GCN layer 1 GEMM, then fused gather1+GEMM2, fused gather2+placement ----
    k_gemm_nodes<<<12500, 256, 0, stream>>>(x, W1, dinv, A);
    k_gather1<<<12500, 256, 0, stream>>>(A, off, esrc, dinv, b1, W2, B);
    k_gather2<<<12500, 256, 0, stream>>>(B, off, esrc, dinv, b2, Wp1, bp1, Wp2, bp2,
                                         out, emb8);

    // ---- action head (fp8 MFMA) ----
    k_prep<<<128, 256, 0, stream>>>(We1, Wa1, Wa2, Wt8);
    k_action<<<768, 512, 256 * RSTR + 8 * 16 * RSTR, stream>>>(
        emb8, ae, army, Wt8, be1, We2, be2, ba1, ba2, out + NN, out + NN + NA);
}

// Round 7
// 592.080 us; speedup vs baseline: 1.1925x; 1.0334x over previous
//
#include <hip/hip_runtime.h>

#define NN      50000
#define NEDGE   1600000
#define NA      1000000
#define FEATD   128
#define EMBD    64
#define MAXSEND 50
#define RSTR    136   // padded LDS row stride in BYTES (128 fp8 + 8 pad)

// ---- binned CSR build parameters ----
#define BSHIFT  7                 // 128 nodes per bin
#define NBINS   391               // ceil(50000/128)
#define BINCAP  4864              // mean 4096 + ~12 sigma headroom
#define ACHUNK  4096              // edges staged per block in k_binA
#define ABLK    391               // ceil(NEDGE/ACHUNK)

typedef __attribute__((ext_vector_type(4))) float f32x4;

__device__ __forceinline__ unsigned char f2fp8(float f) {
    int p = __builtin_amdgcn_cvt_pk_fp8_f32(f, f, 0, false);
    return (unsigned char)(p & 0xff);
}

// bf16 round-to-nearest-even pack/unpack (unpack is a single shift)
__device__ __forceinline__ unsigned short f2bf16(float f) {
    unsigned int u = __float_as_uint(f);
    unsigned int r = u + 0x7fff + ((u >> 16) & 1);
    return (unsigned short)(r >> 16);
}
__device__ __forceinline__ float bf2f(unsigned short h) {
    return __uint_as_float(((unsigned int)h) << 16);
}

__device__ __forceinline__ int wave_incl_scan(int v, int lane) {
#pragma unroll
    for (int d = 1; d < 64; d <<= 1) {
        int u = __shfl_up(v, d, 64);
        v += (lane >= d) ? u : 0;
    }
    return v;
}

// ---------------- phase A: block-staged scatter of (row,col) into coarse bins ----------------
__launch_bounds__(512)
__global__ void k_binA(const int* __restrict__ row, const int* __restrict__ col,
                       int* __restrict__ bincnt, int2* __restrict__ epair) {
    extern __shared__ char smem[];
    int2* buf   = (int2*)smem;                        // ACHUNK * 8 bytes
    int*  hist  = (int*)(smem + ACHUNK * sizeof(int2));
    int*  lcur  = hist + NBINS;
    int*  delta = lcur + NBINS;
    __shared__ int ws8[8];

    int tid = threadIdx.x;
    for (int i = tid; i < NBINS; i += 512) hist[i] = 0;
    __syncthreads();

    int base = blockIdx.x * ACHUNK;
    int myr[8], myc[8];
#pragma unroll
    for (int j = 0; j < 8; j++) {
        int e = base + j * 512 + tid;
        myc[j] = (e < NEDGE) ? col[e] : -1;
        myr[j] = (e < NEDGE) ? row[e] : 0;
        if (myc[j] >= 0) atomicAdd(&hist[myc[j] >> BSHIFT], 1);
    }
    __syncthreads();

    // exclusive scan of hist (391 values) + reserve global space per bin
    int lane = tid & 63, w = tid >> 6;
    int v = (tid < NBINS) ? hist[tid] : 0;
    int inc = wave_incl_scan(v, lane);
    if (lane == 63) ws8[w] = inc;
    __syncthreads();
    if (tid < NBINS) {
        int add = 0;
        for (int i = 0; i < w; i++) add += ws8[i];
        int excl = add + inc - v;
        lcur[tid] = excl;
        int prior = (v > 0) ? atomicAdd(&bincnt[tid], v) : 0;
        delta[tid] = tid * BINCAP + prior - excl;     // LDS slot s -> global pos s + delta[bin]
    }
    __syncthreads();

    // local scatter into LDS, ordered by bin
#pragma unroll
    for (int j = 0; j < 8; j++) {
        if (myc[j] >= 0) {
            int b = myc[j] >> BSHIFT;
            int p = atomicAdd(&lcur[b], 1);
            buf[p] = make_int2(myr[j], myc[j]);
        }
    }
    __syncthreads();

    // coalesced run-writes to global bins
    int total = min(ACHUNK, NEDGE - base);
    for (int s = tid; s < total; s += 512) {
        int2 pr = buf[s];
        epair[s + delta[pr.y >> BSHIFT]] = pr;
    }
}

// ---------------- exclusive scan of bin totals (391 values, 1 block) ----------------
__global__ void k_binscan(const int* __restrict__ bincnt, int* __restrict__ binbase) {
    int t = threadIdx.x;                               // 512 threads
    int v = (t < NBINS) ? bincnt[t] : 0;
    int lane = t & 63, w = t >> 6;
    int inc = wave_incl_scan(v, lane);
    __shared__ int ws8[8];
    if (lane == 63) ws8[w] = inc;
    __syncthreads();
    int add = 0;
    for (int i = 0; i < w; i++) add += ws8[i];
    if (t < NBINS) binbase[t] = add + inc - v;
}

// ---------------- phase B: one block per bin -> off, dinv, esrc ----------------
__launch_bounds__(512)
__global__ void k_binB(const int* __restrict__ bincnt, const int* __restrict__ binbase,
                       const int2* __restrict__ epair,
                       int* __restrict__ off, float* __restrict__ dinv,
                       int* __restrict__ esrc) {
    __shared__ int hist[128];
    __shared__ int lcur[128];
    __shared__ int ws8[8];
    int b = blockIdx.x;
    int tid = threadIdx.x;
    int nodes0 = b << BSHIFT;
    int nnodes = min(128, NN - nodes0);
    int n = bincnt[b];
    const int2* src = epair + (long)b * BINCAP;

    if (tid < 128) hist[tid] = 0;
    __syncthreads();
    for (int s = tid; s < n; s += 512)
        atomicAdd(&hist[src[s].y & 127], 1);
    __syncthreads();

    int lane = tid & 63, w = tid >> 6;
    int v = (tid < 128) ? hist[tid] : 0;
    int inc = wave_incl_scan(v, lane);
    if (lane == 63) ws8[w] = inc;
    __syncthreads();
    if (tid < 128) {
        int add = binbase[b];
        for (int i = 0; i < w; i++) add += ws8[i];
        int excl = add + inc - v;
        lcur[tid] = excl;
        if (tid < nnodes) {
            off[nodes0 + tid]  = excl;
            dinv[nodes0 + tid] = rsqrtf((float)(v + 1));   // +1 self loop
        }
    }
    if (b == 0 && tid == 0) off[NN] = NEDGE;
    __syncthreads();

    for (int s = tid; s < n; s += 512) {
        int2 pr = src[s];
        int p = atomicAdd(&lcur[pr.y & 127], 1);
        esrc[p] = pr.x;
    }
}

// ---------------- node GEMM: Hs[v][j] = dinv[v] * sum_k X[v][k] W[k][j], bf16 out ----------------
__global__ void k_gemm_nodes(const float* __restrict__ X, const float* __restrict__ W,
                             const float* __restrict__ dinv,
                             unsigned short* __restrict__ Hs) {
    int wid  = (blockIdx.x * 256 + threadIdx.x) >> 6;  // one wave per node row
    int lane = threadIdx.x & 63;
    const float* xr = X + (long)wid * FEATD;
    float x0 = xr[lane];
    float x1 = xr[lane + 64];
    float acc = 0.f;
#pragma unroll
    for (int k = 0; k < 64; k++) {
        float xv = __shfl(x0, k, 64);
        acc = fmaf(xv, W[k * EMBD + lane], acc);
    }
#pragma unroll
    for (int k = 0; k < 64; k++) {
        float xv = __shfl(x1, k, 64);
        acc = fmaf(xv, W[(k + 64) * EMBD + lane], acc);
    }
    Hs[(long)wid * EMBD + lane] = f2bf16(acc * dinv[wid]);
}

// ---- gather layer 1 (bf16 table: 128B/edge-row instead of 256B) fused with layer-2 GEMM ----
__global__ void k_gather1(const unsigned short* __restrict__ Hs, const int* __restrict__ off,
                          const int* __restrict__ esrc, const float* __restrict__ dinv,
                          const float* __restrict__ b1, const float* __restrict__ W2,
                          unsigned short* __restrict__ Hs2) {
    int wid  = (blockIdx.x * 256 + threadIdx.x) >> 6;  // one wave per node
    int lane = threadIdx.x & 63;
    int beg = off[wid], end = off[wid + 1];
    float acc = bf2f(Hs[(long)wid * EMBD + lane]);     // self loop
    int i = beg;
    for (; i + 4 <= end; i += 4) {
        int r0 = esrc[i], r1 = esrc[i + 1], r2 = esrc[i + 2], r3 = esrc[i + 3];
        unsigned short h0 = Hs[(long)r0 * EMBD + lane];
        unsigned short h1 = Hs[(long)r1 * EMBD + lane];
        unsigned short h2 = Hs[(long)r2 * EMBD + lane];
        unsigned short h3 = Hs[(long)r3 * EMBD + lane];
        acc += bf2f(h0) + bf2f(h1) + bf2f(h2) + bf2f(h3);
    }
    for (; i < end; i++) acc += bf2f(Hs[(long)esrc[i] * EMBD + lane]);
    float d = dinv[wid];
    float h = fmaxf(acc * d + b1[lane], 0.f);
    float a2 = 0.f;
#pragma unroll
    for (int k = 0; k < 64; k++) {
        float hv = __shfl(h, k, 64);
        a2 = fmaf(hv, W2[k * EMBD + lane], a2);
    }
    Hs2[(long)wid * EMBD + lane] = f2bf16(a2 * d);
}

// ---- gather layer 2 (bf16 table) fused with placement head + fp8 emb pack ----
__global__ void k_gather2(const unsigned short* __restrict__ Hs, const int* __restrict__ off,
                          const int* __restrict__ esrc, const float* __restrict__ dinv,
                          const float* __restrict__ b2,
                          const float* __restrict__ Wp1, const float* __restrict__ bp1,
                          const float* __restrict__ Wp2, const float* __restrict__ bp2,
                          float* __restrict__ out_place, unsigned char* __restrict__ emb8) {
    int wid  = (blockIdx.x * 256 + threadIdx.x) >> 6;  // one wave per node
    int lane = threadIdx.x & 63;
    int beg = off[wid], end = off[wid + 1];
    float acc = bf2f(Hs[(long)wid * EMBD + lane]);
    int i = beg;
    for (; i + 4 <= end; i += 4) {
        int r0 = esrc[i], r1 = esrc[i + 1], r2 = esrc[i + 2], r3 = esrc[i + 3];
        unsigned short h0 = Hs[(long)r0 * EMBD + lane];
        unsigned short h1 = Hs[(long)r1 * EMBD + lane];
        unsigned short h2 = Hs[(long)r2 * EMBD + lane];
        unsigned short h3 = Hs[(long)r3 * EMBD + lane];
        acc += bf2f(h0) + bf2f(h1) + bf2f(h2) + bf2f(h3);
    }
    for (; i < end; i++) acc += bf2f(Hs[(long)esrc[i] * EMBD + lane]);
    float o = acc * dinv[wid] + b2[lane];              // emb value (fp32)
    // placement head
    float p = 0.f;
#pragma unroll
    for (int k = 0; k < 64; k++) {
        float ev = __shfl(o, k, 64);
        p = fmaf(ev, Wp1[k * 64 + lane], p);
    }
    p = fmaxf(p + bp1[lane], 0.f) * Wp2[lane];
#pragma unroll
    for (int d = 32; d; d >>= 1) p += __shfl_xor(p, d, 64);
    if (lane == 0) out_place[wid] = p + bp2[0];
    // fp8 pack of emb row (4 lanes -> 1 dword)
    float o1 = __shfl_down(o, 1, 64);
    float o2 = __shfl_down(o, 2, 64);
    float o3 = __shfl_down(o, 3, 64);
    int pk = __builtin_amdgcn_cvt_pk_fp8_f32(o, o1, 0, false);
    pk = __builtin_amdgcn_cvt_pk_fp8_f32(o2, o3, pk, true);
    if ((lane & 3) == 0)
        *(int*)(emb8 + (long)wid * EMBD + lane) = pk;
}

// ---- weight prep: fp8 transposed [n][k]; n: 0-63 We1, 64-191 Wa1, 192-255 Wa2(pad) ----
__global__ void k_prep(const float* __restrict__ We1, const float* __restrict__ Wa1,
                       const float* __restrict__ Wa2, unsigned char* __restrict__ Wt8) {
    int t = blockIdx.x * 256 + threadIdx.x;
    if (t >= 256 * 128) return;
    int n = t >> 7, k = t & 127;
    float v;
    if (n < 64)       v = We1[k * 64 + n];
    else if (n < 192) v = Wa1[k * 128 + (n - 64)];
    else { int n2 = n - 192; v = (n2 < MAXSEND) ? Wa2[k * MAXSEND + n2] : 0.f; }
    Wt8[t] = f2fp8(v);
}

// ---------------- action-edge MLP: fp8 MFMA, one 16-action m-tile per wave ----------------
// R5 structure kept: R0 store scheme (scattered regular stores; L2 merges) + software
// pipeline of the ae->army->emb8 chain (neutral but harmless). Structural floor ~130us.
__launch_bounds__(512, 4)
__global__ void k_action(const unsigned char* __restrict__ emb8, const int* __restrict__ ae,
                         const int* __restrict__ army, const unsigned char* __restrict__ Wt8,
                         const float* __restrict__ be1, const float* __restrict__ We2,
                         const float* __restrict__ be2, const float* __restrict__ ba1,
                         const float* __restrict__ ba2,
                         float* __restrict__ out_edge, float* __restrict__ out_army) {
    extern __shared__ char lds8[];
    int tid = threadIdx.x;
    // stage fp8 weights into padded LDS (256 rows x RSTR bytes)
    for (int i = tid; i < 2048; i += 512) {
        int rw = i >> 3, c16 = (i & 7) * 16;
        *(uint4*)(lds8 + rw * RSTR + c16) = *(const uint4*)(Wt8 + rw * 128 + c16);
    }
    __syncthreads();

    int w = tid >> 6, lane = tid & 63;
    int m = lane & 15, q = lane >> 4;                  // MFMA lane decomposition
    char* a1s = lds8 + 256 * RSTR + w * 16 * RSTR;     // per-wave 16xRSTR fp8 scratch

    float be1v[4], w2v[4], ba1v[8], ba2v[4];
#pragma unroll
    for (int t = 0; t < 4; t++) { be1v[t] = be1[t * 16 + m]; w2v[t] = We2[t * 16 + m]; }
#pragma unroll
    for (int t = 0; t < 8; t++) ba1v[t] = ba1[t * 16 + m];
#pragma unroll
    for (int nt = 0; nt < 4; nt++) { int n = nt * 16 + m; ba2v[nt] = (n < MAXSEND) ? ba2[n] : 0.f; }
    float be2v = be2[0];
    const f32x4 zero = {0.f, 0.f, 0.f, 0.f};

    int gw = blockIdx.x * 8 + w;
    int nwaves = gridDim.x * 8;
    const int NT = NA / 16;

    // ---- pipeline prologue: load tile 0's operands ----
    int tile = gw;
    int2 st = {0, 0};
    int army_s = 0, army_t = 0;
    long af[4] = {0, 0, 0, 0};
    if (tile < NT) {
        st = ((const int2*)ae)[tile * 16 + m];
        army_s = army[st.x];
        army_t = army[st.y];
        af[0] = *(const long*)(emb8 + (long)st.x * EMBD + q * 8);
        af[1] = *(const long*)(emb8 + (long)st.x * EMBD + 32 + q * 8);
        af[2] = *(const long*)(emb8 + (long)st.y * EMBD + q * 8);
        af[3] = *(const long*)(emb8 + (long)st.y * EMBD + 32 + q * 8);
    }

    while (tile < NT) {
        int a0 = tile * 16;
        int next = tile + nwaves;
        // early-issue next tile's ae pair (latency hides under stage-1 MFMA)
        int2 st_n = st;
        if (next < NT) st_n = ((const int2*)ae)[next * 16 + m];

        // per-action mask adjustment from current regs
        float adj_m = ((army_s <= 2) || (army_t >= 3 * army_s)) ? 1.f : 0.f;
        if (st.x == st.y) adj_m += 100.f;
        float adjr[4]; int sar[4];
#pragma unroll
        for (int r = 0; r < 4; r++) {
            int rowlane = q * 4 + r;
            adjr[r] = __shfl(adj_m, rowlane, 64);
            sar[r]  = __shfl(army_s, rowlane, 64);
        }

        // stage 1: n-tiles 0..3 -> e1 (We1 rows), 4..11 -> a1 (Wa1 rows)
        f32x4 acc[12];
#pragma unroll
        for (int t = 0; t < 12; t++) acc[t] = zero;
#pragma unroll
        for (int t = 0; t < 12; t++) {
#pragma unroll
            for (int kk = 0; kk < 4; kk++) {
                long bfrag = *(const long*)(lds8 + (t * 16 + m) * RSTR + kk * 32 + q * 8);
                acc[t] = __builtin_amdgcn_mfma_f32_16x16x32_fp8_fp8(af[kk], bfrag, acc[t], 0, 0, 0);
            }
        }

        // issue next tile's dependent loads NOW (st_n landed during stage-1);
        // their latency hides under epilogues + stage-2
        int army_s_n = army_s, army_t_n = army_t;
        long af_n[4] = {af[0], af[1], af[2], af[3]};
        if (next < NT) {
            army_s_n = army[st_n.x];
            army_t_n = army[st_n.y];
            af_n[0] = *(const long*)(emb8 + (long)st_n.x * EMBD + q * 8);
            af_n[1] = *(const long*)(emb8 + (long)st_n.x * EMBD + 32 + q * 8);
            af_n[2] = *(const long*)(emb8 + (long)st_n.y * EMBD + q * 8);
            af_n[3] = *(const long*)(emb8 + (long)st_n.y * EMBD + 32 + q * 8);
        }

        // e1 epilogue -> edge-logit partials (C layout: row a=q*4+r, col j=t*16+m)
        float elp[4] = {0.f, 0.f, 0.f, 0.f};
#pragma unroll
        for (int t = 0; t < 4; t++) {
#pragma unroll
            for (int r = 0; r < 4; r++) {
                float v = fmaxf(acc[t][r] + be1v[t], 0.f);
                elp[r] = fmaf(v, w2v[t], elp[r]);
            }
        }
        // a1 epilogue -> fp8 into per-wave LDS scratch
#pragma unroll
        for (int t = 4; t < 12; t++) {
#pragma unroll
            for (int r = 0; r < 4; r++) {
                float v = fmaxf(acc[t][r] + ba1v[t - 4], 0.f);
                a1s[(q * 4 + r) * RSTR + (t - 4) * 16 + m] = (char)f2fp8(v);
            }
        }
        // reduce edge logits over the 16 j-lanes in each quad
#pragma unroll
        for (int r = 0; r < 4; r++) {
            float s = elp[r];
            s += __shfl_xor(s, 1, 64);
            s += __shfl_xor(s, 2, 64);
            s += __shfl_xor(s, 4, 64);
            s += __shfl_xor(s, 8, 64);
            elp[r] = s;
        }
        if (m == 0) {
#pragma unroll
            for (int r = 0; r < 4; r++)
                out_edge[a0 + q * 4 + r] = elp[r] + be2v - adjr[r];
        }
        __asm__ volatile("s_waitcnt lgkmcnt(0)" ::: "memory");  // a1s writes -> reads
        // stage 2: army = relu(a1) @ Wa2 (rows 192..255 in LDS, cols padded to 64)
        long a2f[4];
#pragma unroll
        for (int kk = 0; kk < 4; kk++)
            a2f[kk] = *(const long*)(a1s + m * RSTR + kk * 32 + q * 8);
#pragma unroll
        for (int nt = 0; nt < 4; nt++) {
            f32x4 c2 = zero;
#pragma unroll
            for (int kk = 0; kk < 4; kk++) {
                long bfrag = *(const long*)(lds8 + (192 + nt * 16 + m) * RSTR + kk * 32 + q * 8);
                c2 = __builtin_amdgcn_mfma_f32_16x16x32_fp8_fp8(a2f[kk], bfrag, c2, 0, 0, 0);
            }
            int n = nt * 16 + m;
            if (n < MAXSEND) {
#pragma unroll
                for (int r = 0; r < 4; r++) {
                    int aa = a0 + q * 4 + r;
                    float v = c2[r] + ba2v[nt];
                    out_army[(long)aa * MAXSEND + n] = (n < sar[r]) ? v : -1e9f;
                }
            }
        }

        // rotate pipeline registers
        st = st_n; army_s = army_s_n; army_t = army_t_n;
        af[0] = af_n[0]; af[1] = af_n[1]; af[2] = af_n[2]; af[3] = af_n[3];
        tile = next;
    }
}

extern "C" void kernel_launch(void* const* d_in, const int* in_sizes, int n_in,
                              void* d_out, int out_size, void* d_ws, size_t ws_size,
                              hipStream_t stream) {
    const float* x    = (const float*)d_in[0];
    const int*   ei   = (const int*)d_in[1];
    const int*   ae   = (const int*)d_in[2];
    const int*   army = (const int*)d_in[3];
    const float* W1   = (const float*)d_in[4];
    const float* b1   = (const float*)d_in[5];
    const float* W2   = (const float*)d_in[6];
    const float* b2   = (const float*)d_in[7];
    const float* Wp1  = (const float*)d_in[8];
    const float* bp1  = (const float*)d_in[9];
    const float* Wp2  = (const float*)d_in[10];
    const float* bp2  = (const float*)d_in[11];
    const float* We1  = (const float*)d_in[12];
    const float* be1  = (const float*)d_in[13];
    const float* We2  = (const float*)d_in[14];
    const float* be2  = (const float*)d_in[15];
    const float* Wa1  = (const float*)d_in[16];
    const float* ba1  = (const float*)d_in[17];
    const float* Wa2  = (const float*)d_in[18];
    const float* ba2  = (const float*)d_in[19];
    float* out = (float*)d_out;

    char* ws = (char*)d_ws;
    int*            bincnt  = (int*)ws;                        // 391 ints
    int*            binbase = (int*)(ws + 4096);               // 391 ints
    float*          dinv    = (float*)(ws + 200000);           // 50000 f
    int*            off     = (int*)(ws + 400000);             // 50001 ints
    int*            esrc    = (int*)(ws + 800064);             // 1.6M ints
    int2*           epair   = (int2*)(ws + 7200064);           // 391*4864*8 = 15.2MB (transient)
    unsigned short* A       = (unsigned short*)(ws + 7200064); // 50000x64 bf16 (Hs1) - after epair dead
    unsigned short* B       = (unsigned short*)(ws + 24000064);// 50000x64 bf16 (Hs2)
    unsigned char*  emb8    = (unsigned char*)(ws + 32800064); // 50000x64 fp8
    unsigned char*  Wt8     = (unsigned char*)(ws + 36000064); // 256x128 fp8

    // ---- CSR build (once per launch): block-staged two-level binning sort ----
    hipMemsetAsync(bincnt, 0, NBINS * 4, stream);
    k_binA<<<ABLK, 512, ACHUNK * sizeof(int2) + 3 * NBINS * 4, stream>>>(
        ei, ei + NEDGE, bincnt, epair);
    k_binscan<<<1, 512, 0, stream>>>(bincnt, binbase);
    k_binB<<<NBINS, 512, 0, stream>>>(bincnt, binbase, epair, off, dinv, esrc);

    // ---- GCN layer 1 GEMM (bf16 out), fused gather1+GEMM2, fused gather2+placement ----
    k_gemm_nodes<<<12500, 256, 0, stream>>>(x, W1, dinv, A);
    k_gather1<<<12500, 256, 0, stream>>>(A, off, esrc, dinv, b1, W2, B);
    k_gather2<<<12500, 256, 0, stream>>>(B, off, esrc, dinv, b2, Wp1, bp1, Wp2, bp2,
                                         out, emb8);

    // ---- action head (fp8 MFMA) ----
    k_prep<<<128, 256, 0, stream>>>(We1, Wa1, Wa2, Wt8);
    k_action<<<768, 512, 256 * RSTR + 8 * 16 * RSTR, stream>>>(
        emb8, ae, army, Wt8, be1, We2, be2, ba1, ba2, out + NN, out + NN + NA);
}

// Round 9
// 583.676 us; speedup vs baseline: 1.2097x; 1.0144x over previous
//
#include <hip/hip_runtime.h>

#define NN      50000
#define NEDGE   1600000
#define NA      1000000
#define FEATD   128
#define EMBD    64
#define MAXSEND 50
#define RSTR    136   // padded LDS row stride in BYTES (128 fp8 + 8 pad)

// ---- binned CSR build parameters ----
#define BSHIFT  7                 // 128 nodes per bin
#define NBINS   391               // ceil(50000/128)
#define BINCAP  4864              // mean 4096 + ~12 sigma headroom
#define ACHUNK  4096              // edges staged per block in k_binA
#define ABLK    391               // ceil(NEDGE/ACHUNK)

typedef __attribute__((ext_vector_type(4))) float f32x4;

__device__ __forceinline__ unsigned char f2fp8(float f) {
    int p = __builtin_amdgcn_cvt_pk_fp8_f32(f, f, 0, false);
    return (unsigned char)(p & 0xff);
}

// bf16 round-to-nearest-even pack/unpack (unpack is a single shift)
__device__ __forceinline__ unsigned short f2bf16(float f) {
    unsigned int u = __float_as_uint(f);
    unsigned int r = u + 0x7fff + ((u >> 16) & 1);
    return (unsigned short)(r >> 16);
}
__device__ __forceinline__ float bf2f(unsigned short h) {
    return __uint_as_float(((unsigned int)h) << 16);
}

__device__ __forceinline__ int wave_incl_scan(int v, int lane) {
#pragma unroll
    for (int d = 1; d < 64; d <<= 1) {
        int u = __shfl_up(v, d, 64);
        v += (lane >= d) ? u : 0;
    }
    return v;
}

// ---------------- phase A: block-staged scatter of (row,col) into coarse bins ----------------
__launch_bounds__(512)
__global__ void k_binA(const int* __restrict__ row, const int* __restrict__ col,
                       int* __restrict__ bincnt, int2* __restrict__ epair) {
    extern __shared__ char smem[];
    int2* buf   = (int2*)smem;                        // ACHUNK * 8 bytes
    int*  hist  = (int*)(smem + ACHUNK * sizeof(int2));
    int*  lcur  = hist + NBINS;
    int*  delta = lcur + NBINS;
    __shared__ int ws8[8];

    int tid = threadIdx.x;
    for (int i = tid; i < NBINS; i += 512) hist[i] = 0;
    __syncthreads();

    int base = blockIdx.x * ACHUNK;
    int myr[8], myc[8];
#pragma unroll
    for (int j = 0; j < 8; j++) {
        int e = base + j * 512 + tid;
        myc[j] = (e < NEDGE) ? col[e] : -1;
        myr[j] = (e < NEDGE) ? row[e] : 0;
        if (myc[j] >= 0) atomicAdd(&hist[myc[j] >> BSHIFT], 1);
    }
    __syncthreads();

    // exclusive scan of hist (391 values) + reserve global space per bin
    int lane = tid & 63, w = tid >> 6;
    int v = (tid < NBINS) ? hist[tid] : 0;
    int inc = wave_incl_scan(v, lane);
    if (lane == 63) ws8[w] = inc;
    __syncthreads();
    if (tid < NBINS) {
        int add = 0;
        for (int i = 0; i < w; i++) add += ws8[i];
        int excl = add + inc - v;
        lcur[tid] = excl;
        int prior = (v > 0) ? atomicAdd(&bincnt[tid], v) : 0;
        delta[tid] = tid * BINCAP + prior - excl;     // LDS slot s -> global pos s + delta[bin]
    }
    __syncthreads();

    // local scatter into LDS, ordered by bin
#pragma unroll
    for (int j = 0; j < 8; j++) {
        if (myc[j] >= 0) {
            int b = myc[j] >> BSHIFT;
            int p = atomicAdd(&lcur[b], 1);
            buf[p] = make_int2(myr[j], myc[j]);
        }
    }
    __syncthreads();

    // coalesced run-writes to global bins
    int total = min(ACHUNK, NEDGE - base);
    for (int s = tid; s < total; s += 512) {
        int2 pr = buf[s];
        epair[s + delta[pr.y >> BSHIFT]] = pr;
    }
}

// ---------------- exclusive scan of bin totals (391 values, 1 block) ----------------
__global__ void k_binscan(const int* __restrict__ bincnt, int* __restrict__ binbase) {
    int t = threadIdx.x;                               // 512 threads
    int v = (t < NBINS) ? bincnt[t] : 0;
    int lane = t & 63, w = t >> 6;
    int inc = wave_incl_scan(v, lane);
    __shared__ int ws8[8];
    if (lane == 63) ws8[w] = inc;
    __syncthreads();
    int add = 0;
    for (int i = 0; i < w; i++) add += ws8[i];
    if (t < NBINS) binbase[t] = add + inc - v;
}

// ---------------- phase B: one block per bin -> off, dinv, esrc ----------------
__launch_bounds__(512)
__global__ void k_binB(const int* __restrict__ bincnt, const int* __restrict__ binbase,
                       const int2* __restrict__ epair,
                       int* __restrict__ off, float* __restrict__ dinv,
                       int* __restrict__ esrc) {
    __shared__ int hist[128];
    __shared__ int lcur[128];
    __shared__ int ws8[8];
    int b = blockIdx.x;
    int tid = threadIdx.x;
    int nodes0 = b << BSHIFT;
    int nnodes = min(128, NN - nodes0);
    int n = bincnt[b];
    const int2* src = epair + (long)b * BINCAP;

    if (tid < 128) hist[tid] = 0;
    __syncthreads();
    for (int s = tid; s < n; s += 512)
        atomicAdd(&hist[src[s].y & 127], 1);
    __syncthreads();

    int lane = tid & 63, w = tid >> 6;
    int v = (tid < 128) ? hist[tid] : 0;
    int inc = wave_incl_scan(v, lane);
    if (lane == 63) ws8[w] = inc;
    __syncthreads();
    if (tid < 128) {
        int add = binbase[b];
        for (int i = 0; i < w; i++) add += ws8[i];
        int excl = add + inc - v;
        lcur[tid] = excl;
        if (tid < nnodes) {
            off[nodes0 + tid]  = excl;
            dinv[nodes0 + tid] = rsqrtf((float)(v + 1));   // +1 self loop
        }
    }
    if (b == 0 && tid == 0) off[NN] = NEDGE;
    __syncthreads();

    for (int s = tid; s < n; s += 512) {
        int2 pr = src[s];
        int p = atomicAdd(&lcur[pr.y & 127], 1);
        esrc[p] = pr.x;
    }
}

// ---------------- node GEMM: Hs[v][j] = dinv[v] * sum_k X[v][k] W[k][j], bf16 out ----------------
__global__ void k_gemm_nodes(const float* __restrict__ X, const float* __restrict__ W,
                             const float* __restrict__ dinv,
                             unsigned short* __restrict__ Hs) {
    int wid  = (blockIdx.x * 256 + threadIdx.x) >> 6;  // one wave per node row
    int lane = threadIdx.x & 63;
    const float* xr = X + (long)wid * FEATD;
    float x0 = xr[lane];
    float x1 = xr[lane + 64];
    float acc = 0.f;
#pragma unroll
    for (int k = 0; k < 64; k++) {
        float xv = __shfl(x0, k, 64);
        acc = fmaf(xv, W[k * EMBD + lane], acc);
    }
#pragma unroll
    for (int k = 0; k < 64; k++) {
        float xv = __shfl(x1, k, 64);
        acc = fmaf(xv, W[(k + 64) * EMBD + lane], acc);
    }
    Hs[(long)wid * EMBD + lane] = f2bf16(acc * dinv[wid]);
}

// ---- quad-row gather core: lane's quarter (lane>>4) owns every 4th edge; lane reads
// 8B = 4 bf16 cols of that row per load -> 1 instruction fetches 4 edge-rows (512B).
// acc[c] holds col 4*(lane&15)+c, partial over this quarter's edges.
#define GATHER_GROUP(R0, R1, R2, R3)                                                   \
    {                                                                                  \
        int ra = (qq == 0) ? (R0) : (qq == 1) ? (R1) : (qq == 2) ? (R2) : (R3);        \
        unsigned long long va =                                                        \
            *(const unsigned long long*)(Hs + (long)ra * EMBD + cl * 4);               \
        unsigned int lo = (unsigned int)va, hi = (unsigned int)(va >> 32);             \
        ac0 += __uint_as_float(lo << 16);                                              \
        ac1 += __uint_as_float(lo & 0xffff0000u);                                      \
        ac2 += __uint_as_float(hi << 16);                                              \
        ac3 += __uint_as_float(hi & 0xffff0000u);                                      \
    }

// ---- gather layer 1 (bf16 table, quad-row loads) fused with layer-2 GEMM ----
__global__ void k_gather1(const unsigned short* __restrict__ Hs, const int* __restrict__ off,
                          const int* __restrict__ esrc, const float* __restrict__ dinv,
                          const float* __restrict__ b1, const float* __restrict__ W2,
                          unsigned short* __restrict__ Hs2) {
    int wid  = (blockIdx.x * 256 + threadIdx.x) >> 6;  // one wave per node
    int lane = threadIdx.x & 63;
    int qq   = lane >> 4;                              // quarter: which of 4 rows
    int cl   = lane & 15;                              // 4-col group within row
    int beg = off[wid], end = off[wid + 1];
    float ac0 = 0.f, ac1 = 0.f, ac2 = 0.f, ac3 = 0.f;
    int i = beg;
    for (; i + 8 <= end; i += 8) {                     // 2 groups = 8 rows in flight
        int r0 = esrc[i],     r1 = esrc[i + 1], r2 = esrc[i + 2], r3 = esrc[i + 3];
        int s0 = esrc[i + 4], s1 = esrc[i + 5], s2 = esrc[i + 6], s3 = esrc[i + 7];
        GATHER_GROUP(r0, r1, r2, r3)
        GATHER_GROUP(s0, s1, s2, s3)
    }
    for (; i + 4 <= end; i += 4) {
        int r0 = esrc[i], r1 = esrc[i + 1], r2 = esrc[i + 2], r3 = esrc[i + 3];
        GATHER_GROUP(r0, r1, r2, r3)
    }
    int tail = end - i;
    if (tail > 0) {                                    // masked group for 1-3 edges
        int r0 = esrc[i];
        int r1 = (tail > 1) ? esrc[i + 1] : r0;
        int r2 = (tail > 2) ? esrc[i + 2] : r0;
        int ra = (qq == 0) ? r0 : (qq == 1) ? r1 : (qq == 2) ? r2 : r0;
        unsigned long long va = *(const unsigned long long*)(Hs + (long)ra * EMBD + cl * 4);
        float msk = (qq < tail) ? 1.f : 0.f;
        unsigned int lo = (unsigned int)va, hi = (unsigned int)(va >> 32);
        ac0 = fmaf(__uint_as_float(lo << 16), msk, ac0);
        ac1 = fmaf(__uint_as_float(lo & 0xffff0000u), msk, ac1);
        ac2 = fmaf(__uint_as_float(hi << 16), msk, ac2);
        ac3 = fmaf(__uint_as_float(hi & 0xffff0000u), msk, ac3);
    }
    // combine quarters (lanes differing in bits 4,5)
    ac0 += __shfl_xor(ac0, 16, 64); ac0 += __shfl_xor(ac0, 32, 64);
    ac1 += __shfl_xor(ac1, 16, 64); ac1 += __shfl_xor(ac1, 32, 64);
    ac2 += __shfl_xor(ac2, 16, 64); ac2 += __shfl_xor(ac2, 32, 64);
    ac3 += __shfl_xor(ac3, 16, 64); ac3 += __shfl_xor(ac3, 32, 64);
    // remap to col=lane: col j lives at lane j>>2, component j&3
    float v0 = __shfl(ac0, lane >> 2, 64);
    float v1 = __shfl(ac1, lane >> 2, 64);
    float v2 = __shfl(ac2, lane >> 2, 64);
    float v3 = __shfl(ac3, lane >> 2, 64);
    int c = lane & 3;
    float acc = (c == 0) ? v0 : (c == 1) ? v1 : (c == 2) ? v2 : v3;
    acc += bf2f(Hs[(long)wid * EMBD + lane]);          // self loop
    float d = dinv[wid];
    float h = fmaxf(acc * d + b1[lane], 0.f);
    float a2 = 0.f;
#pragma unroll
    for (int k = 0; k < 64; k++) {
        float hv = __shfl(h, k, 64);
        a2 = fmaf(hv, W2[k * EMBD + lane], a2);
    }
    Hs2[(long)wid * EMBD + lane] = f2bf16(a2 * d);
}

// ---- gather layer 2 (bf16 table, quad-row loads) fused with placement head + fp8 pack ----
__global__ void k_gather2(const unsigned short* __restrict__ Hs, const int* __restrict__ off,
                          const int* __restrict__ esrc, const float* __restrict__ dinv,
                          const float* __restrict__ b2,
                          const float* __restrict__ Wp1, const float* __restrict__ bp1,
                          const float* __restrict__ Wp2, const float* __restrict__ bp2,
                          float* __restrict__ out_place, unsigned char* __restrict__ emb8) {
    int wid  = (blockIdx.x * 256 + threadIdx.x) >> 6;  // one wave per node
    int lane = threadIdx.x & 63;
    int qq   = lane >> 4;
    int cl   = lane & 15;
    int beg = off[wid], end = off[wid + 1];
    float ac0 = 0.f, ac1 = 0.f, ac2 = 0.f, ac3 = 0.f;
    int i = beg;
    for (; i + 8 <= end; i += 8) {
        int r0 = esrc[i],     r1 = esrc[i + 1], r2 = esrc[i + 2], r3 = esrc[i + 3];
        int s0 = esrc[i + 4], s1 = esrc[i + 5], s2 = esrc[i + 6], s3 = esrc[i + 7];
        GATHER_GROUP(r0, r1, r2, r3)
        GATHER_GROUP(s0, s1, s2, s3)
    }
    for (; i + 4 <= end; i += 4) {
        int r0 = esrc[i], r1 = esrc[i + 1], r2 = esrc[i + 2], r3 = esrc[i + 3];
        GATHER_GROUP(r0, r1, r2, r3)
    }
    int tail = end - i;
    if (tail > 0) {
        int r0 = esrc[i];
        int r1 = (tail > 1) ? esrc[i + 1] : r0;
        int r2 = (tail > 2) ? esrc[i + 2] : r0;
        int ra = (qq == 0) ? r0 : (qq == 1) ? r1 : (qq == 2) ? r2 : r0;
        unsigned long long va = *(const unsigned long long*)(Hs + (long)ra * EMBD + cl * 4);
        float msk = (qq < tail) ? 1.f : 0.f;
        unsigned int lo = (unsigned int)va, hi = (unsigned int)(va >> 32);
        ac0 = fmaf(__uint_as_float(lo << 16), msk, ac0);
        ac1 = fmaf(__uint_as_float(lo & 0xffff0000u), msk, ac1);
        ac2 = fmaf(__uint_as_float(hi << 16), msk, ac2);
        ac3 = fmaf(__uint_as_float(hi & 0xffff0000u), msk, ac3);
    }
    ac0 += __shfl_xor(ac0, 16, 64); ac0 += __shfl_xor(ac0, 32, 64);
    ac1 += __shfl_xor(ac1, 16, 64); ac1 += __shfl_xor(ac1, 32, 64);
    ac2 += __shfl_xor(ac2, 16, 64); ac2 += __shfl_xor(ac2, 32, 64);
    ac3 += __shfl_xor(ac3, 16, 64); ac3 += __shfl_xor(ac3, 32, 64);
    float v0 = __shfl(ac0, lane >> 2, 64);
    float v1 = __shfl(ac1, lane >> 2, 64);
    float v2 = __shfl(ac2, lane >> 2, 64);
    float v3 = __shfl(ac3, lane >> 2, 64);
    int c = lane & 3;
    float acc = (c == 0) ? v0 : (c == 1) ? v1 : (c == 2) ? v2 : v3;
    acc += bf2f(Hs[(long)wid * EMBD + lane]);          // self loop
    float o = acc * dinv[wid] + b2[lane];              // emb value (fp32)
    // placement head
    float p = 0.f;
#pragma unroll
    for (int k = 0; k < 64; k++) {
        float ev = __shfl(o, k, 64);
        p = fmaf(ev, Wp1[k * 64 + lane], p);
    }
    p = fmaxf(p + bp1[lane], 0.f) * Wp2[lane];
#pragma unroll
    for (int d = 32; d; d >>= 1) p += __shfl_xor(p, d, 64);
    if (lane == 0) out_place[wid] = p + bp2[0];
    // fp8 pack of emb row (4 lanes -> 1 dword)
    float o1 = __shfl_down(o, 1, 64);
    float o2 = __shfl_down(o, 2, 64);
    float o3 = __shfl_down(o, 3, 64);
    int pk = __builtin_amdgcn_cvt_pk_fp8_f32(o, o1, 0, false);
    pk = __builtin_amdgcn_cvt_pk_fp8_f32(o2, o3, pk, true);
    if ((lane & 3) == 0)
        *(int*)(emb8 + (long)wid * EMBD + lane) = pk;
}

// ---- weight prep: fp8 transposed [n][k]; n: 0-63 We1, 64-191 Wa1, 192-255 Wa2(pad) ----
__global__ void k_prep(const float* __restrict__ We1, const float* __restrict__ Wa1,
                       const float* __restrict__ Wa2, unsigned char* __restrict__ Wt8) {
    int t = blockIdx.x * 256 + threadIdx.x;
    if (t >= 256 * 128) return;
    int n = t >> 7, k = t & 127;
    float v;
    if (n < 64)       v = We1[k * 64 + n];
    else if (n < 192) v = Wa1[k * 128 + (n - 64)];
    else { int n2 = n - 192; v = (n2 < MAXSEND) ? Wa2[k * MAXSEND + n2] : 0.f; }
    Wt8[t] = f2fp8(v);
}

// ---------------- action-edge MLP: fp8 MFMA, one 16-action m-tile per wave ----------------
// R5 structure kept: R0 store scheme (scattered regular stores; L2 merges) + software
// pipeline of the ae->army->emb8 chain (neutral but harmless). Structural floor ~130us.
__launch_bounds__(512, 4)
__global__ void k_action(const unsigned char* __restrict__ emb8, const int* __restrict__ ae,
                         const int* __restrict__ army, const unsigned char* __restrict__ Wt8,
                         const float* __restrict__ be1, const float* __restrict__ We2,
                         const float* __restrict__ be2, const float* __restrict__ ba1,
                         const float* __restrict__ ba2,
                         float* __restrict__ out_edge, float* __restrict__ out_army) {
    extern __shared__ char lds8[];
    int tid = threadIdx.x;
    // stage fp8 weights into padded LDS (256 rows x RSTR bytes)
    for (int i = tid; i < 2048; i += 512) {
        int rw = i >> 3, c16 = (i & 7) * 16;
        *(uint4*)(lds8 + rw * RSTR + c16) = *(const uint4*)(Wt8 + rw * 128 + c16);
    }
    __syncthreads();

    int w = tid >> 6, lane = tid & 63;
    int m = lane & 15, q = lane >> 4;                  // MFMA lane decomposition
    char* a1s = lds8 + 256 * RSTR + w * 16 * RSTR;     // per-wave 16xRSTR fp8 scratch

    float be1v[4], w2v[4], ba1v[8], ba2v[4];
#pragma unroll
    for (int t = 0; t < 4; t++) { be1v[t] = be1[t * 16 + m]; w2v[t] = We2[t * 16 + m]; }
#pragma unroll
    for (int t = 0; t < 8; t++) ba1v[t] = ba1[t * 16 + m];
#pragma unroll
    for (int nt = 0; nt < 4; nt++) { int n = nt * 16 + m; ba2v[nt] = (n < MAXSEND) ? ba2[n] : 0.f; }
    float be2v = be2[0];
    const f32x4 zero = {0.f, 0.f, 0.f, 0.f};

    int gw = blockIdx.x * 8 + w;
    int nwaves = gridDim.x * 8;
    const int NT = NA / 16;

    // ---- pipeline prologue: load tile 0's operands ----
    int tile = gw;
    int2 st = {0, 0};
    int army_s = 0, army_t = 0;
    long af[4] = {0, 0, 0, 0};
    if (tile < NT) {
        st = ((const int2*)ae)[tile * 16 + m];
        army_s = army[st.x];
        army_t = army[st.y];
        af[0] = *(const long*)(emb8 + (long)st.x * EMBD + q * 8);
        af[1] = *(const long*)(emb8 + (long)st.x * EMBD + 32 + q * 8);
        af[2] = *(const long*)(emb8 + (long)st.y * EMBD + q * 8);
        af[3] = *(const long*)(emb8 + (long)st.y * EMBD + 32 + q * 8);
    }

    while (tile < NT) {
        int a0 = tile * 16;
        int next = tile + nwaves;
        // early-issue next tile's ae pair (latency hides under stage-1 MFMA)
        int2 st_n = st;
        if (next < NT) st_n = ((const int2*)ae)[next * 16 + m];

        // per-action mask adjustment from current regs
        float adj_m = ((army_s <= 2) || (army_t >= 3 * army_s)) ? 1.f : 0.f;
        if (st.x == st.y) adj_m += 100.f;
        float adjr[4]; int sar[4];
#pragma unroll
        for (int r = 0; r < 4; r++) {
            int rowlane = q * 4 + r;
            adjr[r] = __shfl(adj_m, rowlane, 64);
            sar[r]  = __shfl(army_s, rowlane, 64);
        }

        // stage 1: n-tiles 0..3 -> e1 (We1 rows), 4..11 -> a1 (Wa1 rows)
        f32x4 acc[12];
#pragma unroll
        for (int t = 0; t < 12; t++) acc[t] = zero;
#pragma unroll
        for (int t = 0; t < 12; t++) {
#pragma unroll
            for (int kk = 0; kk < 4; kk++) {
                long bfrag = *(const long*)(lds8 + (t * 16 + m) * RSTR + kk * 32 + q * 8);
                acc[t] = __builtin_amdgcn_mfma_f32_16x16x32_fp8_fp8(af[kk], bfrag, acc[t], 0, 0, 0);
            }
        }

        // issue next tile's dependent loads NOW (st_n landed during stage-1);
        // their latency hides under epilogues + stage-2
        int army_s_n = army_s, army_t_n = army_t;
        long af_n[4] = {af[0], af[1], af[2], af[3]};
        if (next < NT) {
            army_s_n = army[st_n.x];
            army_t_n = army[st_n.y];
            af_n[0] = *(const long*)(emb8 + (long)st_n.x * EMBD + q * 8);
            af_n[1] = *(const long*)(emb8 + (long)st_n.x * EMBD + 32 + q * 8);
            af_n[2] = *(const long*)(emb8 + (long)st_n.y * EMBD + q * 8);
            af_n[3] = *(const long*)(emb8 + (long)st_n.y * EMBD + 32 + q * 8);
        }

        // e1 epilogue -> edge-logit partials (C layout: row a=q*4+r, col j=t*16+m)
        float elp[4] = {0.f, 0.f, 0.f, 0.f};
#pragma unroll
        for (int t = 0; t < 4; t++) {
#pragma unroll
            for (int r = 0; r < 4; r++) {
                float v = fmaxf(acc[t][r] + be1v[t], 0.f);
                elp[r] = fmaf(v, w2v[t], elp[r]);
            }
        }
        // a1 epilogue -> fp8 into per-wave LDS scratch
#pragma unroll
        for (int t = 4; t < 12; t++) {
#pragma unroll
            for (int r = 0; r < 4; r++) {
                float v = fmaxf(acc[t][r] + ba1v[t - 4], 0.f);
                a1s[(q * 4 + r) * RSTR + (t - 4) * 16 + m] = (char)f2fp8(v);
            }
        }
        // reduce edge logits over the 16 j-lanes in each quad
#pragma unroll
        for (int r = 0; r < 4; r++) {
            float s = elp[r];
            s += __shfl_xor(s, 1, 64);
            s += __shfl_xor(s, 2, 64);
            s += __shfl_xor(s, 4, 64);
            s += __shfl_xor(s, 8, 64);
            elp[r] = s;
        }
        if (m == 0) {
#pragma unroll
            for (int r = 0; r < 4; r++)
                out_edge[a0 + q * 4 + r] = elp[r] + be2v - adjr[r];
        }
        __asm__ volatile("s_waitcnt lgkmcnt(0)" ::: "memory");  // a1s writes -> reads
        // stage 2: army = relu(a1) @ Wa2 (rows 192..255 in LDS, cols padded to 64)
        long a2f[4];
#pragma unroll
        for (int kk = 0; kk < 4; kk++)
            a2f[kk] = *(const long*)(a1s + m * RSTR + kk * 32 + q * 8);
#pragma unroll
        for (int nt = 0; nt < 4; nt++) {
            f32x4 c2 = zero;
#pragma unroll
            for (int kk = 0; kk < 4; kk++) {
                long bfrag = *(const long*)(lds8 + (192 + nt * 16 + m) * RSTR + kk * 32 + q * 8);
                c2 = __builtin_amdgcn_mfma_f32_16x16x32_fp8_fp8(a2f[kk], bfrag, c2, 0, 0, 0);
            }
            int n = nt * 16 + m;
            if (n < MAXSEND) {
#pragma unroll
                for (int r = 0; r < 4; r++) {
                    int aa = a0 + q * 4 + r;
                    float v = c2[r] + ba2v[nt];
                    out_army[(long)aa * MAXSEND + n] = (n < sar[r]) ? v : -1e9f;
                }
            }
        }

        // rotate pipeline registers
        st = st_n; army_s = army_s_n; army_t = army_t_n;
        af[0] = af_n[0]; af[1] = af_n[1]; af[2] = af_n[2]; af[3] = af_n[3];
        tile = next;
    }
}

extern "C" void kernel_launch(void* const* d_in, const int* in_sizes, int n_in,
                              void* d_out, int out_size, void* d_ws, size_t ws_size,
                              hipStream_t stream) {
    const float* x    = (const float*)d_in[0];
    const int*   ei   = (const int*)d_in[1];
    const int*   ae   = (const int*)d_in[2];
    const int*   army = (const int*)d_in[3];
    const float* W1   = (const float*)d_in[4];
    const float* b1   = (const float*)d_in[5];
    const float* W2   = (const float*)d_in[6];
    const float* b2   = (const float*)d_in[7];
    const float* Wp1  = (const float*)d_in[8];
    const float* bp1  = (const float*)d_in[9];
    const float* Wp2  = (const float*)d_in[10];
    const float* bp2  = (const float*)d_in[11];
    const float* We1  = (const float*)d_in[12];
    const float* be1  = (const float*)d_in[13];
    const float* We2  = (const float*)d_in[14];
    const float* be2  = (const float*)d_in[15];
    const float* Wa1  = (const float*)d_in[16];
    const float* ba1  = (const float*)d_in[17];
    const float* Wa2  = (const float*)d_in[18];
    const float* ba2  = (const float*)d_in[19];
    float* out = (float*)d_out;

    char* ws = (char*)d_ws;
    int*            bincnt  = (int*)ws;                        // 391 ints
    int*            binbase = (int*)(ws + 4096);               // 391 ints
    float*          dinv    = (float*)(ws + 200000);           // 50000 f
    int*            off     = (int*)(ws + 400000);             // 50001 ints
    int*            esrc    = (int*)(ws + 800064);             // 1.6M ints
    int2*           epair   = (int2*)(ws + 7200064);           // 391*4864*8 = 15.2MB (transient)
    unsigned short* A       = (unsigned short*)(ws + 7200064); // 50000x64 bf16 (Hs1) - after epair dead
    unsigned short* B       = (unsigned short*)(ws + 24000064);// 50000x64 bf16 (Hs2)
    unsigned char*  emb8    = (unsigned char*)(ws + 32800064); // 50000x64 fp8
    unsigned char*  Wt8     = (unsigned char*)(ws + 36000064); // 256x128 fp8

    // ---- CSR build (once per launch): block-staged two-level binning sort ----
    hipMemsetAsync(bincnt, 0, NBINS * 4, stream);
    k_binA<<<ABLK, 512, ACHUNK * sizeof(int2) + 3 * NBINS * 4, stream>>>(
        ei, ei + NEDGE, bincnt, epair);
    k_binscan<<<1, 512, 0, stream>>>(bincnt, binbase);
    k_binB<<<NBINS, 512, 0, stream>>>(bincnt, binbase, epair, off, dinv, esrc);

    // ---- GCN layer 1 GEMM (bf16 out), fused gather1+GEMM2, fused gather2+placement ----
    k_gemm_nodes<<<12500, 256, 0, stream>>>(x, W1, dinv, A);
    k_gather1<<<12500, 256, 0, stream>>>(A, off, esrc, dinv, b1, W2, B);
    k_gather2<<<12500, 256, 0, stream>>>(B, off, esrc, dinv, b2, Wp1, bp1, Wp2, bp2,
                                         out, emb8);

    // ---- action head (fp8 MFMA) ----
    k_prep<<<128, 256, 0, stream>>>(We1, Wa1, Wa2, Wt8);
    k_action<<<768, 512, 256 * RSTR + 8 * 16 * RSTR, stream>>>(
        emb8, ae, army, Wt8, be1, We2, be2, ba1, ba2, out + NN, out + NN + NA);
}